// Round 3
// baseline (5662.060 us; speedup 1.0000x reference)
//
#include <hip/hip_runtime.h>
#include <math.h>

#define Bn 128
#define Tn 256
#define Fn 36
#define Hn 128
#define F2n 72
#define G4 512
#define BTFn (Bn*Tn*Fn)

// workspace layout (floats)
#define INVD_OFF 0
#define LOSS_OFF 102656
#define IMP_OFF  103040

__device__ __forceinline__ float sigmoid_f(float x) {
    return __builtin_amdgcn_rcpf(1.f + __expf(-x));
}
__device__ __forceinline__ float tanh_f(float x) {
    return fmaf(2.f, __builtin_amdgcn_rcpf(1.f + __expf(-2.f * x)), -1.f);
}

// ---------------- prep: inv-denom per t ----------------
__global__ void prep_kernel(const float* __restrict__ data,
                            float* __restrict__ ws) {
    int t = blockIdx.x;          // 0..255
    int tid = threadIdx.x;
    __shared__ float red[256];
    float s = 0.f;
    for (int idx = tid; idx < Bn * Fn; idx += 256) {
        int b = idx / Fn, f = idx - b * Fn;
        s += data[((size_t)(b * 24 + 1) * Tn + t) * Fn + f];
    }
    red[tid] = s;
    __syncthreads();
    for (int off = 128; off > 0; off >>= 1) {
        if (tid < off) red[tid] += red[tid + off];
        __syncthreads();
    }
    if (tid == 0) ws[INVD_OFF + t] = 1.f / (red[0] + 1e-5f);
}

// ---------------- main: one block = 2 chains, gate weights in registers ----------------
// NOTE: no min-waves arg — a 512-thread block forces <=256 VGPR (2 waves/SIMD),
// which is exactly the budget the 200-VGPR weight array needs. (512,2) capped
// allocation at 128 VGPR and spilled (round-2 post-mortem).
__global__ __launch_bounds__(512) void rits_main(
    const float* __restrict__ data,
    const float* __restrict__ W_dh, const float* __restrict__ b_dh,
    const float* __restrict__ W_dx, const float* __restrict__ b_dx,
    const float* __restrict__ W_hist, const float* __restrict__ b_hist,
    const float* __restrict__ W_feat, const float* __restrict__ b_feat,
    const float* __restrict__ W_wc, const float* __restrict__ b_wc,
    const float* __restrict__ W_ih, const float* __restrict__ W_hh,
    const float* __restrict__ b_ih, const float* __restrict__ b_hh,
    const float* __restrict__ W_comb,
    float* __restrict__ ws) {

    const int tid = threadIdx.x;
    const int chain0 = blockIdx.x * 2;
    const int chainSel = tid >> 8;      // 0: chain A, 1: chain B
    const int st = tid & 255;
    const int myChain = chain0 + chainSel;
    const int b = myChain / 3, k = myChain - 3 * (myChain / 3);

    __shared__ float Wdh_s[Hn][Fn + 1];
    __shared__ float Whist_s[Fn][Hn + 1];
    __shared__ float Wf_s[Fn][Fn + 1];
    __shared__ float Wwc_s[Fn][F2n + 1];
    __shared__ __align__(16) float h_s[2][Hn];
    __shared__ float gates_s[2][G4];
    __shared__ float in_s[2][2][5][Fn];         // [parity][chain][m,d,rt,tr,se][f]
    __shared__ float xh_s[2][Fn], xc_s[2][Fn], alpha_s[2][Fn], gx_s[2][Fn];
    __shared__ __align__(16) float inp_s[2][F2n];
    __shared__ float bdh_s[Hn];
    __shared__ float bh_s[Fn], bf_s[Fn], bwc_s[Fn], wdxd_s[Fn], bdx_s[Fn];
    __shared__ float invd_s[Tn];

    // ---- one-time LDS staging ----
    for (int i = tid; i < Hn * Fn; i += 512) Wdh_s[i / Fn][i % Fn] = W_dh[i];
    for (int i = tid; i < Fn * Hn; i += 512) Whist_s[i / Hn][i % Hn] = W_hist[i];
    for (int i = tid; i < Fn * Fn; i += 512) {
        int r = i / Fn, c = i - r * Fn;
        Wf_s[r][c] = (r == c) ? 0.f : W_feat[i];
    }
    for (int i = tid; i < Fn * F2n; i += 512) Wwc_s[i / F2n][i % F2n] = W_wc[i];
    if (tid < Hn) bdh_s[tid] = b_dh[tid];
    if (st < Hn) h_s[chainSel][st] = 0.f;
    if (tid < Fn) {
        bh_s[tid] = b_hist[tid]; bf_s[tid] = b_feat[tid]; bwc_s[tid] = b_wc[tid];
        wdxd_s[tid] = W_dx[tid * (Fn + 1)]; bdx_s[tid] = b_dx[tid];
    }
    for (int i = tid; i < Tn; i += 512) invd_s[i] = ws[INVD_OFF + i];

    // ---- gate weights for row j into registers (once) ----
    const int j = tid;
    float4 w[50];
    {
        const float4* wi = (const float4*)(W_ih + j * F2n);   // 288B rows, 16B aligned
        #pragma unroll
        for (int q = 0; q < 18; ++q) w[q] = wi[q];
        const float4* wh = (const float4*)(W_hh + j * Hn);    // 512B rows
        #pragma unroll
        for (int q = 0; q < 32; ++q) w[18 + q] = wh[q];
    }
    const float bias_j = b_ih[j] + b_hh[j];

    // ---- input loader roles (threads st in [128,256) load own chain's inputs) ----
    const float* ldsrc0 = nullptr; float* lddst0 = nullptr;
    const float* ldsrc1 = nullptr; float* lddst1 = nullptr;
    if (st >= 128) {
        int idx = st - 128;                       // 0..127
        int which = idx / Fn, f = idx - which * Fn;
        int row = (which == 0) ? 1 : (which == 1) ? 2 : (3 + 3 * k + (which - 2));
        ldsrc0 = data + (size_t)(b * 24 + row) * Tn * Fn + f;
        lddst0 = &in_s[0][chainSel][which][f];
        int idx2 = idx + 128;                     // 128..255
        if (idx2 < 180) {
            int which2 = idx2 / Fn, f2 = idx2 - which2 * Fn;
            int row2 = (which2 == 0) ? 1 : (which2 == 1) ? 2 : (3 + 3 * k + (which2 - 2));
            ldsrc1 = data + (size_t)(b * 24 + row2) * Tn * Fn + f2;
            lddst1 = &in_s[0][chainSel][which2][f2];
        }
    }
    // prologue: load t=0 inputs into parity 0
    if (lddst0) *lddst0 = ldsrc0[0];
    if (lddst1) *lddst1 = ldsrc1[0];

    float c_reg = 0.f;
    float loss_acc = 0.f;
    float gaccA = 0.f, gaccB = 0.f;
    float* imp_b = ws + IMP_OFF + (size_t)(k * Bn + b) * Tn * Fn;

    __syncthreads();

    for (int t = 0; t < Tn; ++t) {
        const int cur = t & 1, nxt = cur ^ 1;
        const float* inc = &in_s[cur][chainSel][0][0];   // [which][f] flat, stride Fn

        // ---- P2: decay h; gamma_x ----
        if (st < Hn) {
            float acc = bdh_s[st];
            #pragma unroll
            for (int f = 0; f < Fn; ++f) acc = fmaf(inc[Fn + f], Wdh_s[st][f], acc);
            h_s[chainSel][st] *= __expf(-fmaxf(acc, 0.f));
        } else if (st < 128 + Fn) {
            int f = st - 128;
            gx_s[chainSel][f] = __expf(-fmaxf(fmaf(inc[Fn + f], wdxd_s[f], bdx_s[f]), 0.f));
        }
        __syncthreads();

        // ---- issue next-step input loads (latency hides under P3..P5) ----
        float pf0 = 0.f, pf1 = 0.f;
        if (lddst0) pf0 = ldsrc0[(size_t)(t + 1) * Fn];
        if (lddst1) pf1 = ldsrc1[(size_t)(t + 1) * Fn];

        // ---- P3: x_h/x_c (st<36); alpha (64<=st<100); gate h-part chain A (all) ----
        if (st < Fn) {
            float a0 = bh_s[st], a1 = 0.f, a2 = 0.f, a3 = 0.f;
            #pragma unroll
            for (int hh = 0; hh < Hn; hh += 4) {
                a0 = fmaf(h_s[chainSel][hh],     Whist_s[st][hh],     a0);
                a1 = fmaf(h_s[chainSel][hh + 1], Whist_s[st][hh + 1], a1);
                a2 = fmaf(h_s[chainSel][hh + 2], Whist_s[st][hh + 2], a2);
                a3 = fmaf(h_s[chainSel][hh + 3], Whist_s[st][hh + 3], a3);
            }
            float xh = (a0 + a1) + (a2 + a3);
            xh_s[chainSel][st] = xh;
            float m = inc[st], rt = inc[2 * Fn + st];
            xc_s[chainSel][st] = m * rt + (1.f - m) * xh;
        } else if (st >= 64 && st < 64 + Fn) {
            int g = st - 64;
            float a = bwc_s[g];
            #pragma unroll
            for (int f = 0; f < Fn; ++f) a = fmaf(gx_s[chainSel][f], Wwc_s[g][f], a);
            #pragma unroll
            for (int f = 0; f < Fn; ++f) a = fmaf(inc[f], Wwc_s[g][Fn + f], a);
            alpha_s[chainSel][g] = a;
        }
        {   // gate h-part, chain A (broadcast LDS reads)
            const float4* h4 = (const float4*)(&h_s[0][0]);
            float a0 = 0.f, a1 = 0.f, a2 = 0.f, a3 = 0.f;
            #pragma unroll
            for (int q = 0; q < 32; ++q) {
                float4 x = h4[q];
                a0 = fmaf(x.x, w[18 + q].x, a0);
                a1 = fmaf(x.y, w[18 + q].y, a1);
                a2 = fmaf(x.z, w[18 + q].z, a2);
                a3 = fmaf(x.w, w[18 + q].w, a3);
            }
            gaccA = (a0 + a1) + (a2 + a3);
        }
        __syncthreads();

        // ---- P4: z_h/c_h/c_c/inp/loss/imp (st<36); gate h-part chain B (all) ----
        if (st < Fn) {
            float a = bf_s[st];
            #pragma unroll
            for (int f = 0; f < Fn; ++f) a = fmaf(xc_s[chainSel][f], Wf_s[st][f], a);
            float zh = a;
            float al = alpha_s[chainSel][st], xh = xh_s[chainSel][st];
            float ch = al * zh + (1.f - al) * xh;
            float m = inc[st], rt = inc[2 * Fn + st];
            float cc = m * rt + (1.f - m) * ch;
            inp_s[chainSel][st] = cc;
            inp_s[chainSel][Fn + st] = m;
            loss_acc = fmaf((fabsf(rt - xh) + fabsf(rt - zh) + fabsf(rt - ch)) * m,
                            invd_s[t], loss_acc);
            imp_b[t * Fn + st] = cc + inc[4 * Fn + st] + inc[3 * Fn + st];
        }
        {   // gate h-part, chain B
            const float4* h4 = (const float4*)(&h_s[1][0]);
            float a0 = 0.f, a1 = 0.f, a2 = 0.f, a3 = 0.f;
            #pragma unroll
            for (int q = 0; q < 32; ++q) {
                float4 x = h4[q];
                a0 = fmaf(x.x, w[18 + q].x, a0);
                a1 = fmaf(x.y, w[18 + q].y, a1);
                a2 = fmaf(x.z, w[18 + q].z, a2);
                a3 = fmaf(x.w, w[18 + q].w, a3);
            }
            gaccB = (a0 + a1) + (a2 + a3);
        }
        __syncthreads();

        // ---- P5: gate inp-part, both chains (all threads, row j) ----
        {
            const float4* xA = (const float4*)(&inp_s[0][0]);
            float a0 = gaccA + bias_j, a1 = 0.f, a2 = 0.f, a3 = 0.f;
            #pragma unroll
            for (int q = 0; q < 18; ++q) {
                float4 x = xA[q];
                a0 = fmaf(x.x, w[q].x, a0);
                a1 = fmaf(x.y, w[q].y, a1);
                a2 = fmaf(x.z, w[q].z, a2);
                a3 = fmaf(x.w, w[q].w, a3);
            }
            gates_s[0][j] = (a0 + a1) + (a2 + a3);
            const float4* xB = (const float4*)(&inp_s[1][0]);
            float b0 = gaccB + bias_j, b1 = 0.f, b2 = 0.f, b3 = 0.f;
            #pragma unroll
            for (int q = 0; q < 18; ++q) {
                float4 x = xB[q];
                b0 = fmaf(x.x, w[q].x, b0);
                b1 = fmaf(x.y, w[q].y, b1);
                b2 = fmaf(x.z, w[q].z, b2);
                b3 = fmaf(x.w, w[q].w, b3);
            }
            gates_s[1][j] = (b0 + b1) + (b2 + b3);
        }
        __syncthreads();

        // ---- P6: LSTM (st<128) ; loaders write prefetched t+1 inputs (st>=128) ----
        if (st < Hn) {
            float ig = gates_s[chainSel][st],      fg = gates_s[chainSel][Hn + st];
            float gg = gates_s[chainSel][2 * Hn + st], og = gates_s[chainSel][3 * Hn + st];
            c_reg = sigmoid_f(fg) * c_reg + sigmoid_f(ig) * tanh_f(gg);
            h_s[chainSel][st] = sigmoid_f(og) * tanh_f(c_reg);
        } else {
            // parity-buffered LDS write of the prefetched values (360 floats/parity)
            lddst0[nxt * 360] = pf0;
            if (lddst1) lddst1[nxt * 360] = pf1;
        }
        __syncthreads();
    }

    // ---- per-chain loss partial (fixed order -> deterministic) ----
    float wkk;
    {
        float w0 = W_comb[0], w1 = W_comb[1], w2 = W_comb[2];
        float mx = fmaxf(w0, fmaxf(w1, w2));
        float e0 = expf(w0 - mx), e1 = expf(w1 - mx), e2 = expf(w2 - mx);
        wkk = ((k == 0) ? e0 : (k == 1) ? e1 : e2) / (e0 + e1 + e2);
    }
    if (st < Fn) gates_s[chainSel][st] = loss_acc;
    __syncthreads();
    if (st == 0) {
        float s = 0.f;
        for (int i = 0; i < Fn; ++i) s += gates_s[chainSel][i];
        ws[LOSS_OFF + myChain] = s * wkk;
    }
}

// ---------------- k-reduction of imputations ----------------
__global__ void impute_reduce(const float* __restrict__ ws,
                              const float* __restrict__ W_comb,
                              float* __restrict__ out) {
    int idx = blockIdx.x * 256 + threadIdx.x;   // < BTFn exactly
    float w0 = W_comb[0], w1 = W_comb[1], w2 = W_comb[2];
    float mx = fmaxf(w0, fmaxf(w1, w2));
    float e0 = expf(w0 - mx), e1 = expf(w1 - mx), e2 = expf(w2 - mx);
    float inv = 1.f / (e0 + e1 + e2);
    const float* imp = ws + IMP_OFF;
    out[1 + idx] = (e0 * imp[idx] + e1 * imp[BTFn + idx] + e2 * imp[2 * BTFn + idx]) * inv;
}

// ---------------- final loss ----------------
__global__ void loss_final(const float* __restrict__ ws,
                           const float* __restrict__ W_comb,
                           float* __restrict__ out) {
    int tid = threadIdx.x;
    __shared__ float red[256];
    const float* lp = ws + LOSS_OFF;
    float s = lp[tid];
    if (tid < 128) s += lp[tid + 256];
    red[tid] = s;
    __syncthreads();
    for (int off = 128; off > 0; off >>= 1) {
        if (tid < off) red[tid] += red[tid + off];
        __syncthreads();
    }
    if (tid == 0) {
        float w0 = W_comb[0], w1 = W_comb[1], w2 = W_comb[2];
        float mx = fmaxf(w0, fmaxf(w1, w2));
        float e0 = expf(w0 - mx), e1 = expf(w1 - mx), e2 = expf(w2 - mx);
        float inv = 1.f / (e0 + e1 + e2);
        float wk0 = e0 * inv, wk1 = e1 * inv, wk2 = e2 * inv;
        float reg = 0.1f * (wk0 * (1.f / 24.f) + wk1 * (1.f / 168.f) + wk2 * (1.f / 720.f));
        out[0] = red[0] + (float)Tn * reg;
    }
}

extern "C" void kernel_launch(void* const* d_in, const int* in_sizes, int n_in,
                              void* d_out, int out_size, void* d_ws, size_t ws_size,
                              hipStream_t stream) {
    const float* data   = (const float*)d_in[0];
    const float* W_dh   = (const float*)d_in[1];
    const float* b_dh   = (const float*)d_in[2];
    const float* W_dx   = (const float*)d_in[3];
    const float* b_dx   = (const float*)d_in[4];
    const float* W_hist = (const float*)d_in[5];
    const float* b_hist = (const float*)d_in[6];
    const float* W_feat = (const float*)d_in[7];
    const float* b_feat = (const float*)d_in[8];
    const float* W_wc   = (const float*)d_in[9];
    const float* b_wc   = (const float*)d_in[10];
    const float* W_ih   = (const float*)d_in[11];
    const float* W_hh   = (const float*)d_in[12];
    const float* b_ih   = (const float*)d_in[13];
    const float* b_hh   = (const float*)d_in[14];
    const float* W_comb = (const float*)d_in[15];
    float* ws = (float*)d_ws;
    float* out = (float*)d_out;

    hipLaunchKernelGGL(prep_kernel, dim3(Tn), dim3(256), 0, stream, data, ws);
    hipLaunchKernelGGL(rits_main, dim3(Bn * 3 / 2), dim3(512), 0, stream,
                       data, W_dh, b_dh, W_dx, b_dx, W_hist, b_hist,
                       W_feat, b_feat, W_wc, b_wc, W_ih, W_hh, b_ih, b_hh, W_comb, ws);
    hipLaunchKernelGGL(impute_reduce, dim3(BTFn / 256), dim3(256), 0, stream, ws, W_comb, out);
    hipLaunchKernelGGL(loss_final, dim3(1), dim3(256), 0, stream, ws, W_comb, out);
}

// Round 4
// 5653.259 us; speedup vs baseline: 1.0016x; 1.0016x over previous
//
#include <hip/hip_runtime.h>
#include <math.h>

#define Bn 128
#define Tn 256
#define Fn 36
#define Hn 128
#define F2n 72
#define G4 512
#define BTFn (Bn*Tn*Fn)

// workspace layout (floats)
#define INVD_OFF 0
#define LOSS_OFF 102656
#define IMP_OFF  103040

__device__ __forceinline__ float sigmoid_f(float x) {
    return __builtin_amdgcn_rcpf(1.f + __expf(-x));
}
__device__ __forceinline__ float tanh_f(float x) {
    return fmaf(2.f, __builtin_amdgcn_rcpf(1.f + __expf(-2.f * x)), -1.f);
}

// ---------------- prep: inv-denom per t ----------------
__global__ void prep_kernel(const float* __restrict__ data,
                            float* __restrict__ ws) {
    int t = blockIdx.x;          // 0..255
    int tid = threadIdx.x;
    __shared__ float red[256];
    float s = 0.f;
    for (int idx = tid; idx < Bn * Fn; idx += 256) {
        int b = idx / Fn, f = idx - b * Fn;
        s += data[((size_t)(b * 24 + 1) * Tn + t) * Fn + f];
    }
    red[tid] = s;
    __syncthreads();
    for (int off = 128; off > 0; off >>= 1) {
        if (tid < off) red[tid] += red[tid + off];
        __syncthreads();
    }
    if (tid == 0) ws[INVD_OFF + t] = 1.f / (red[0] + 1e-5f);
}

// ---------------- main: one block = 2 chains, gate weights in registers ----------------
// VGPR budget control (round-3 post-mortem): default heuristic budgets 4 waves/EU
// -> 128 VGPR -> the 200-reg weight array spills to scratch (11 GB/dispatch HBM).
// Pin exactly 2 waves/EU -> 256-VGPR budget -> no spill.
__global__ void
__attribute__((amdgpu_flat_work_group_size(512, 512), amdgpu_waves_per_eu(2, 2)))
rits_main(
    const float* __restrict__ data,
    const float* __restrict__ W_dh, const float* __restrict__ b_dh,
    const float* __restrict__ W_dx, const float* __restrict__ b_dx,
    const float* __restrict__ W_hist, const float* __restrict__ b_hist,
    const float* __restrict__ W_feat, const float* __restrict__ b_feat,
    const float* __restrict__ W_wc, const float* __restrict__ b_wc,
    const float* __restrict__ W_ih, const float* __restrict__ W_hh,
    const float* __restrict__ b_ih, const float* __restrict__ b_hh,
    const float* __restrict__ W_comb,
    float* __restrict__ ws) {

    const int tid = threadIdx.x;
    const int chain0 = blockIdx.x * 2;
    const int chainSel = tid >> 8;      // 0: chain A, 1: chain B
    const int st = tid & 255;
    const int myChain = chain0 + chainSel;
    const int b = myChain / 3, k = myChain - 3 * (myChain / 3);

    __shared__ float Wdh_s[Hn][Fn + 1];
    __shared__ float Whist_s[Fn][Hn + 1];
    __shared__ float Wf_s[Fn][Fn + 1];
    __shared__ float Wwc_s[Fn][F2n + 1];
    __shared__ __align__(16) float h_s[2][Hn];
    __shared__ float gates_s[2][G4];
    __shared__ float in_s[2][2][5][Fn];         // [parity][chain][m,d,rt,tr,se][f]
    __shared__ float xh_s[2][Fn], xc_s[2][Fn], alpha_s[2][Fn], gx_s[2][Fn];
    __shared__ __align__(16) float inp_s[2][F2n];
    __shared__ float bdh_s[Hn];
    __shared__ float bh_s[Fn], bf_s[Fn], bwc_s[Fn], wdxd_s[Fn], bdx_s[Fn];
    __shared__ float invd_s[Tn];

    // ---- one-time LDS staging ----
    for (int i = tid; i < Hn * Fn; i += 512) Wdh_s[i / Fn][i % Fn] = W_dh[i];
    for (int i = tid; i < Fn * Hn; i += 512) Whist_s[i / Hn][i % Hn] = W_hist[i];
    for (int i = tid; i < Fn * Fn; i += 512) {
        int r = i / Fn, c = i - r * Fn;
        Wf_s[r][c] = (r == c) ? 0.f : W_feat[i];
    }
    for (int i = tid; i < Fn * F2n; i += 512) Wwc_s[i / F2n][i % F2n] = W_wc[i];
    if (tid < Hn) bdh_s[tid] = b_dh[tid];
    if (st < Hn) h_s[chainSel][st] = 0.f;
    if (tid < Fn) {
        bh_s[tid] = b_hist[tid]; bf_s[tid] = b_feat[tid]; bwc_s[tid] = b_wc[tid];
        wdxd_s[tid] = W_dx[tid * (Fn + 1)]; bdx_s[tid] = b_dx[tid];
    }
    for (int i = tid; i < Tn; i += 512) invd_s[i] = ws[INVD_OFF + i];

    // ---- gate weights for row j into registers (once) ----
    const int j = tid;
    float4 w[50];
    {
        const float4* wi = (const float4*)(W_ih + j * F2n);   // 288B rows, 16B aligned
        #pragma unroll
        for (int q = 0; q < 18; ++q) w[q] = wi[q];
        const float4* wh = (const float4*)(W_hh + j * Hn);    // 512B rows
        #pragma unroll
        for (int q = 0; q < 32; ++q) w[18 + q] = wh[q];
    }
    const float bias_j = b_ih[j] + b_hh[j];

    // ---- input loader roles (threads st in [128,256) load own chain's inputs) ----
    const float* ldsrc0 = nullptr; float* lddst0 = nullptr;
    const float* ldsrc1 = nullptr; float* lddst1 = nullptr;
    if (st >= 128) {
        int idx = st - 128;                       // 0..127
        int which = idx / Fn, f = idx - which * Fn;
        int row = (which == 0) ? 1 : (which == 1) ? 2 : (3 + 3 * k + (which - 2));
        ldsrc0 = data + (size_t)(b * 24 + row) * Tn * Fn + f;
        lddst0 = &in_s[0][chainSel][which][f];
        int idx2 = idx + 128;                     // 128..255
        if (idx2 < 180) {
            int which2 = idx2 / Fn, f2 = idx2 - which2 * Fn;
            int row2 = (which2 == 0) ? 1 : (which2 == 1) ? 2 : (3 + 3 * k + (which2 - 2));
            ldsrc1 = data + (size_t)(b * 24 + row2) * Tn * Fn + f2;
            lddst1 = &in_s[0][chainSel][which2][f2];
        }
    }
    // prologue: load t=0 inputs into parity 0
    if (lddst0) *lddst0 = ldsrc0[0];
    if (lddst1) *lddst1 = ldsrc1[0];

    float c_reg = 0.f;
    float loss_acc = 0.f;
    float gaccA = 0.f, gaccB = 0.f;
    float* imp_b = ws + IMP_OFF + (size_t)(k * Bn + b) * Tn * Fn;

    __syncthreads();

    for (int t = 0; t < Tn; ++t) {
        const int cur = t & 1, nxt = cur ^ 1;
        const float* inc = &in_s[cur][chainSel][0][0];   // [which][f] flat, stride Fn

        // ---- P2: decay h; gamma_x ----
        if (st < Hn) {
            float acc = bdh_s[st];
            #pragma unroll
            for (int f = 0; f < Fn; ++f) acc = fmaf(inc[Fn + f], Wdh_s[st][f], acc);
            h_s[chainSel][st] *= __expf(-fmaxf(acc, 0.f));
        } else if (st < 128 + Fn) {
            int f = st - 128;
            gx_s[chainSel][f] = __expf(-fmaxf(fmaf(inc[Fn + f], wdxd_s[f], bdx_s[f]), 0.f));
        }
        __syncthreads();

        // ---- issue next-step input loads (latency hides under P3..P5) ----
        float pf0 = 0.f, pf1 = 0.f;
        if (lddst0) pf0 = ldsrc0[(size_t)(t + 1) * Fn];
        if (lddst1) pf1 = ldsrc1[(size_t)(t + 1) * Fn];

        // ---- P3: x_h/x_c (st<36); alpha (64<=st<100); gate h-part chain A (all) ----
        if (st < Fn) {
            float a0 = bh_s[st], a1 = 0.f, a2 = 0.f, a3 = 0.f;
            #pragma unroll
            for (int hh = 0; hh < Hn; hh += 4) {
                a0 = fmaf(h_s[chainSel][hh],     Whist_s[st][hh],     a0);
                a1 = fmaf(h_s[chainSel][hh + 1], Whist_s[st][hh + 1], a1);
                a2 = fmaf(h_s[chainSel][hh + 2], Whist_s[st][hh + 2], a2);
                a3 = fmaf(h_s[chainSel][hh + 3], Whist_s[st][hh + 3], a3);
            }
            float xh = (a0 + a1) + (a2 + a3);
            xh_s[chainSel][st] = xh;
            float m = inc[st], rt = inc[2 * Fn + st];
            xc_s[chainSel][st] = m * rt + (1.f - m) * xh;
        } else if (st >= 64 && st < 64 + Fn) {
            int g = st - 64;
            float a = bwc_s[g];
            #pragma unroll
            for (int f = 0; f < Fn; ++f) a = fmaf(gx_s[chainSel][f], Wwc_s[g][f], a);
            #pragma unroll
            for (int f = 0; f < Fn; ++f) a = fmaf(inc[f], Wwc_s[g][Fn + f], a);
            alpha_s[chainSel][g] = a;
        }
        {   // gate h-part, chain A (broadcast LDS reads)
            const float4* h4 = (const float4*)(&h_s[0][0]);
            float a0 = 0.f, a1 = 0.f, a2 = 0.f, a3 = 0.f;
            #pragma unroll
            for (int q = 0; q < 32; ++q) {
                float4 x = h4[q];
                a0 = fmaf(x.x, w[18 + q].x, a0);
                a1 = fmaf(x.y, w[18 + q].y, a1);
                a2 = fmaf(x.z, w[18 + q].z, a2);
                a3 = fmaf(x.w, w[18 + q].w, a3);
            }
            gaccA = (a0 + a1) + (a2 + a3);
        }
        __syncthreads();

        // ---- P4: z_h/c_h/c_c/inp/loss/imp (st<36); gate h-part chain B (all) ----
        if (st < Fn) {
            float a = bf_s[st];
            #pragma unroll
            for (int f = 0; f < Fn; ++f) a = fmaf(xc_s[chainSel][f], Wf_s[st][f], a);
            float zh = a;
            float al = alpha_s[chainSel][st], xh = xh_s[chainSel][st];
            float ch = al * zh + (1.f - al) * xh;
            float m = inc[st], rt = inc[2 * Fn + st];
            float cc = m * rt + (1.f - m) * ch;
            inp_s[chainSel][st] = cc;
            inp_s[chainSel][Fn + st] = m;
            loss_acc = fmaf((fabsf(rt - xh) + fabsf(rt - zh) + fabsf(rt - ch)) * m,
                            invd_s[t], loss_acc);
            imp_b[t * Fn + st] = cc + inc[4 * Fn + st] + inc[3 * Fn + st];
        }
        {   // gate h-part, chain B
            const float4* h4 = (const float4*)(&h_s[1][0]);
            float a0 = 0.f, a1 = 0.f, a2 = 0.f, a3 = 0.f;
            #pragma unroll
            for (int q = 0; q < 32; ++q) {
                float4 x = h4[q];
                a0 = fmaf(x.x, w[18 + q].x, a0);
                a1 = fmaf(x.y, w[18 + q].y, a1);
                a2 = fmaf(x.z, w[18 + q].z, a2);
                a3 = fmaf(x.w, w[18 + q].w, a3);
            }
            gaccB = (a0 + a1) + (a2 + a3);
        }
        __syncthreads();

        // ---- P5: gate inp-part, both chains (all threads, row j) ----
        {
            const float4* xA = (const float4*)(&inp_s[0][0]);
            float a0 = gaccA + bias_j, a1 = 0.f, a2 = 0.f, a3 = 0.f;
            #pragma unroll
            for (int q = 0; q < 18; ++q) {
                float4 x = xA[q];
                a0 = fmaf(x.x, w[q].x, a0);
                a1 = fmaf(x.y, w[q].y, a1);
                a2 = fmaf(x.z, w[q].z, a2);
                a3 = fmaf(x.w, w[q].w, a3);
            }
            gates_s[0][j] = (a0 + a1) + (a2 + a3);
            const float4* xB = (const float4*)(&inp_s[1][0]);
            float b0 = gaccB + bias_j, b1 = 0.f, b2 = 0.f, b3 = 0.f;
            #pragma unroll
            for (int q = 0; q < 18; ++q) {
                float4 x = xB[q];
                b0 = fmaf(x.x, w[q].x, b0);
                b1 = fmaf(x.y, w[q].y, b1);
                b2 = fmaf(x.z, w[q].z, b2);
                b3 = fmaf(x.w, w[q].w, b3);
            }
            gates_s[1][j] = (b0 + b1) + (b2 + b3);
        }
        __syncthreads();

        // ---- P6: LSTM (st<128) ; loaders write prefetched t+1 inputs (st>=128) ----
        if (st < Hn) {
            float ig = gates_s[chainSel][st],      fg = gates_s[chainSel][Hn + st];
            float gg = gates_s[chainSel][2 * Hn + st], og = gates_s[chainSel][3 * Hn + st];
            c_reg = sigmoid_f(fg) * c_reg + sigmoid_f(ig) * tanh_f(gg);
            h_s[chainSel][st] = sigmoid_f(og) * tanh_f(c_reg);
        } else {
            // parity-buffered LDS write of the prefetched values (360 floats/parity)
            lddst0[nxt * 360] = pf0;
            if (lddst1) lddst1[nxt * 360] = pf1;
        }
        __syncthreads();
    }

    // ---- per-chain loss partial (fixed order -> deterministic) ----
    float wkk;
    {
        float w0 = W_comb[0], w1 = W_comb[1], w2 = W_comb[2];
        float mx = fmaxf(w0, fmaxf(w1, w2));
        float e0 = expf(w0 - mx), e1 = expf(w1 - mx), e2 = expf(w2 - mx);
        wkk = ((k == 0) ? e0 : (k == 1) ? e1 : e2) / (e0 + e1 + e2);
    }
    if (st < Fn) gates_s[chainSel][st] = loss_acc;
    __syncthreads();
    if (st == 0) {
        float s = 0.f;
        for (int i = 0; i < Fn; ++i) s += gates_s[chainSel][i];
        ws[LOSS_OFF + myChain] = s * wkk;
    }
}

// ---------------- k-reduction of imputations ----------------
__global__ void impute_reduce(const float* __restrict__ ws,
                              const float* __restrict__ W_comb,
                              float* __restrict__ out) {
    int idx = blockIdx.x * 256 + threadIdx.x;   // < BTFn exactly
    float w0 = W_comb[0], w1 = W_comb[1], w2 = W_comb[2];
    float mx = fmaxf(w0, fmaxf(w1, w2));
    float e0 = expf(w0 - mx), e1 = expf(w1 - mx), e2 = expf(w2 - mx);
    float inv = 1.f / (e0 + e1 + e2);
    const float* imp = ws + IMP_OFF;
    out[1 + idx] = (e0 * imp[idx] + e1 * imp[BTFn + idx] + e2 * imp[2 * BTFn + idx]) * inv;
}

// ---------------- final loss ----------------
__global__ void loss_final(const float* __restrict__ ws,
                           const float* __restrict__ W_comb,
                           float* __restrict__ out) {
    int tid = threadIdx.x;
    __shared__ float red[256];
    const float* lp = ws + LOSS_OFF;
    float s = lp[tid];
    if (tid < 128) s += lp[tid + 256];
    red[tid] = s;
    __syncthreads();
    for (int off = 128; off > 0; off >>= 1) {
        if (tid < off) red[tid] += red[tid + off];
        __syncthreads();
    }
    if (tid == 0) {
        float w0 = W_comb[0], w1 = W_comb[1], w2 = W_comb[2];
        float mx = fmaxf(w0, fmaxf(w1, w2));
        float e0 = expf(w0 - mx), e1 = expf(w1 - mx), e2 = expf(w2 - mx);
        float inv = 1.f / (e0 + e1 + e2);
        float wk0 = e0 * inv, wk1 = e1 * inv, wk2 = e2 * inv;
        float reg = 0.1f * (wk0 * (1.f / 24.f) + wk1 * (1.f / 168.f) + wk2 * (1.f / 720.f));
        out[0] = red[0] + (float)Tn * reg;
    }
}

extern "C" void kernel_launch(void* const* d_in, const int* in_sizes, int n_in,
                              void* d_out, int out_size, void* d_ws, size_t ws_size,
                              hipStream_t stream) {
    const float* data   = (const float*)d_in[0];
    const float* W_dh   = (const float*)d_in[1];
    const float* b_dh   = (const float*)d_in[2];
    const float* W_dx   = (const float*)d_in[3];
    const float* b_dx   = (const float*)d_in[4];
    const float* W_hist = (const float*)d_in[5];
    const float* b_hist = (const float*)d_in[6];
    const float* W_feat = (const float*)d_in[7];
    const float* b_feat = (const float*)d_in[8];
    const float* W_wc   = (const float*)d_in[9];
    const float* b_wc   = (const float*)d_in[10];
    const float* W_ih   = (const float*)d_in[11];
    const float* W_hh   = (const float*)d_in[12];
    const float* b_ih   = (const float*)d_in[13];
    const float* b_hh   = (const float*)d_in[14];
    const float* W_comb = (const float*)d_in[15];
    float* ws = (float*)d_ws;
    float* out = (float*)d_out;

    hipLaunchKernelGGL(prep_kernel, dim3(Tn), dim3(256), 0, stream, data, ws);
    hipLaunchKernelGGL(rits_main, dim3(Bn * 3 / 2), dim3(512), 0, stream,
                       data, W_dh, b_dh, W_dx, b_dx, W_hist, b_hist,
                       W_feat, b_feat, W_wc, b_wc, W_ih, W_hh, b_ih, b_hh, W_comb, ws);
    hipLaunchKernelGGL(impute_reduce, dim3(BTFn / 256), dim3(256), 0, stream, ws, W_comb, out);
    hipLaunchKernelGGL(loss_final, dim3(1), dim3(256), 0, stream, ws, W_comb, out);
}

// Round 5
// 2110.745 us; speedup vs baseline: 2.6825x; 2.6783x over previous
//
#include <hip/hip_runtime.h>
#include <math.h>

#define Bn 128
#define Tn 256
#define Fn 36
#define Hn 128
#define F2n 72
#define G4 512
#define BTFn (Bn*Tn*Fn)

// workspace layout (floats)
#define INVD_OFF 0
#define LOSS_OFF 102656
#define IMP_OFF  103040

__device__ __forceinline__ float sigmoid_f(float x) {
    return __builtin_amdgcn_rcpf(1.f + __expf(-x));
}
__device__ __forceinline__ float tanh_f(float x) {
    return fmaf(2.f, __builtin_amdgcn_rcpf(1.f + __expf(-2.f * x)), -1.f);
}

// ---------------- prep: inv-denom per t ----------------
__global__ void prep_kernel(const float* __restrict__ data,
                            float* __restrict__ ws) {
    int t = blockIdx.x;          // 0..255
    int tid = threadIdx.x;
    __shared__ float red[256];
    float s = 0.f;
    for (int idx = tid; idx < Bn * Fn; idx += 256) {
        int b = idx / Fn, f = idx - b * Fn;
        s += data[((size_t)(b * 24 + 1) * Tn + t) * Fn + f];
    }
    red[tid] = s;
    __syncthreads();
    for (int off = 128; off > 0; off >>= 1) {
        if (tid < off) red[tid] += red[tid + off];
        __syncthreads();
    }
    if (tid == 0) ws[INVD_OFF + t] = 1.f / (red[0] + 1e-5f);
}

// ---------------- main: 1024 threads, 2 chains, SPLIT-K gate rows ----------------
// Round-4 post-mortem: the allocator pins 512-thread kernels at 128 VGPR no
// matter what attributes we pass -> the 200-reg weight array always spilled
// (11 GB/dispatch scratch traffic). Fix: each thread holds HALF a gate row
// (25 float4 = 100 VGPR), 1024 threads cover 512 rows x 2 halves. 128-VGPR
// budget is now sufficient by construction.
__global__ __launch_bounds__(1024) void rits_main(
    const float* __restrict__ data,
    const float* __restrict__ W_dh, const float* __restrict__ b_dh,
    const float* __restrict__ W_dx, const float* __restrict__ b_dx,
    const float* __restrict__ W_hist, const float* __restrict__ b_hist,
    const float* __restrict__ W_feat, const float* __restrict__ b_feat,
    const float* __restrict__ W_wc, const float* __restrict__ b_wc,
    const float* __restrict__ W_ih, const float* __restrict__ W_hh,
    const float* __restrict__ b_ih, const float* __restrict__ b_hh,
    const float* __restrict__ W_comb,
    float* __restrict__ ws) {

    const int tid = threadIdx.x;          // 0..1023
    const int grp = tid >> 8;             // 0..3
    const int st  = tid & 255;
    const int j    = tid & 511;           // gate row (0..511)
    const int half = tid >> 9;            // 0: K[0:100), 1: K[100:200)
    const int c    = grp & 1;             // chain handled by this group's roles
    const int chain0 = blockIdx.x * 2;
    const int myChain = chain0 + c;
    const int b = myChain / 3, k = myChain - 3 * (myChain / 3);

    __shared__ float Wdh_s[Hn][Fn + 1];
    __shared__ float Whist_s[Fn][Hn + 1];
    __shared__ float Wf_s[Fn][Fn + 1];
    __shared__ float Wwc_s[Fn][F2n + 1];
    __shared__ __align__(16) float h_s[2][Hn];
    __shared__ float gpart_s[2][2][G4];         // [chain][half][row]
    __shared__ float in_s[2][2][5][Fn];         // [parity][chain][m,d,rt,tr,se][f]
    __shared__ float xh_s[2][Fn], xc_s[2][Fn], alpha_s[2][Fn], gx_s[2][Fn];
    __shared__ __align__(16) float inp_s[2][F2n];
    __shared__ float bdh_s[Hn];
    __shared__ float bh_s[Fn], bf_s[Fn], bwc_s[Fn], wdxd_s[Fn], bdx_s[Fn];
    __shared__ float invd_s[Tn];

    // ---- one-time LDS staging ----
    for (int i = tid; i < Hn * Fn; i += 1024) Wdh_s[i / Fn][i % Fn] = W_dh[i];
    for (int i = tid; i < Fn * Hn; i += 1024) Whist_s[i / Hn][i % Hn] = W_hist[i];
    for (int i = tid; i < Fn * Fn; i += 1024) {
        int r = i / Fn, cc = i - r * Fn;
        Wf_s[r][cc] = (r == cc) ? 0.f : W_feat[i];
    }
    for (int i = tid; i < Fn * F2n; i += 1024) Wwc_s[i / F2n][i % F2n] = W_wc[i];
    if (tid < Hn) bdh_s[tid] = b_dh[tid];
    if (tid < 2 * Hn) h_s[tid >> 7][tid & 127] = 0.f;
    if (tid < Fn) {
        bh_s[tid] = b_hist[tid]; bf_s[tid] = b_feat[tid]; bwc_s[tid] = b_wc[tid];
        wdxd_s[tid] = W_dx[tid * (Fn + 1)]; bdx_s[tid] = b_dx[tid];
    }
    for (int i = tid; i < Tn; i += 1024) invd_s[i] = ws[INVD_OFF + i];

    // ---- HALF a gate row into registers (25 float4 = 100 VGPR) ----
    float4 w[25];
    if (half == 0) {
        const float4* wi = (const float4*)(W_ih + j * F2n);   // 72 floats
        #pragma unroll
        for (int q = 0; q < 18; ++q) w[q] = wi[q];
        const float4* wh = (const float4*)(W_hh + j * Hn);    // h[0:28)
        #pragma unroll
        for (int q = 0; q < 7; ++q) w[18 + q] = wh[q];
    } else {
        const float4* wh = (const float4*)(W_hh + j * Hn + 28); // h[28:128), 112B-aligned
        #pragma unroll
        for (int q = 0; q < 25; ++q) w[q] = wh[q];
    }
    const float bias_j = (half == 0) ? (b_ih[j] + b_hh[j]) : 0.f;

    // ---- loader roles: grp>=2, st<180 loads one element of chain c's inputs ----
    const float* ldsrc = nullptr; float* lddst = nullptr;
    if (grp >= 2 && st < 180) {
        int which = st / Fn, f = st - which * Fn;
        int row = (which == 0) ? 1 : (which == 1) ? 2 : (3 + 3 * k + (which - 2));
        ldsrc = data + (size_t)(b * 24 + row) * Tn * Fn + f;
        lddst = &in_s[0][c][which][f];
        *lddst = ldsrc[0];                      // prologue: t=0 into parity 0
    }

    float c_reg = 0.f;
    float loss_acc = 0.f;
    float* imp_b = ws + IMP_OFF + (size_t)(k * Bn + b) * Tn * Fn;

    __syncthreads();

    for (int t = 0; t < Tn; ++t) {
        const int cur = t & 1, nxt = cur ^ 1;
        const float* inc = &in_s[cur][c][0][0];   // this group's chain, stride Fn

        // ---- issue next-step input loads (hide under P2..P5) ----
        float pf = 0.f;
        if (lddst) pf = ldsrc[(size_t)(t + 1) * Fn];

        // ---- P2: decay h; gamma_x (grp 0/1) ----
        if (grp < 2) {
            if (st < Hn) {
                float acc = bdh_s[st];
                #pragma unroll
                for (int f = 0; f < Fn; ++f) acc = fmaf(inc[Fn + f], Wdh_s[st][f], acc);
                h_s[c][st] *= __expf(-fmaxf(acc, 0.f));
            } else if (st < 128 + Fn) {
                int f = st - 128;
                gx_s[c][f] = __expf(-fmaxf(fmaf(inc[Fn + f], wdxd_s[f], bdx_s[f]), 0.f));
            }
        }
        __syncthreads();

        // ---- P3: x_h/x_c + alpha (grp 0/1) ; gate h-part dots (grp 2/3, half 1) ----
        if (grp < 2) {
            if (st < Fn) {
                float a0 = bh_s[st], a1 = 0.f, a2 = 0.f, a3 = 0.f;
                #pragma unroll
                for (int hh = 0; hh < Hn; hh += 4) {
                    a0 = fmaf(h_s[c][hh],     Whist_s[st][hh],     a0);
                    a1 = fmaf(h_s[c][hh + 1], Whist_s[st][hh + 1], a1);
                    a2 = fmaf(h_s[c][hh + 2], Whist_s[st][hh + 2], a2);
                    a3 = fmaf(h_s[c][hh + 3], Whist_s[st][hh + 3], a3);
                }
                float xh = (a0 + a1) + (a2 + a3);
                xh_s[c][st] = xh;
                float m = inc[st], rt = inc[2 * Fn + st];
                xc_s[c][st] = m * rt + (1.f - m) * xh;
            } else if (st >= 64 && st < 64 + Fn) {
                int g = st - 64;
                float a = bwc_s[g];
                #pragma unroll
                for (int f = 0; f < Fn; ++f) a = fmaf(gx_s[c][f], Wwc_s[g][f], a);
                #pragma unroll
                for (int f = 0; f < Fn; ++f) a = fmaf(inc[f], Wwc_s[g][Fn + f], a);
                alpha_s[c][g] = a;
            }
        } else {
            // half==1: h[28:128) partial dot, both chains (h is final after P2)
            const float4* hA = (const float4*)(&h_s[0][28]);
            float a0 = 0.f, a1 = 0.f, a2 = 0.f, a3 = 0.f;
            #pragma unroll
            for (int q = 0; q < 25; ++q) {
                float4 x = hA[q];
                a0 = fmaf(x.x, w[q].x, a0); a1 = fmaf(x.y, w[q].y, a1);
                a2 = fmaf(x.z, w[q].z, a2); a3 = fmaf(x.w, w[q].w, a3);
            }
            gpart_s[0][1][j] = (a0 + a1) + (a2 + a3);
            const float4* hB = (const float4*)(&h_s[1][28]);
            float b0 = 0.f, b1 = 0.f, b2 = 0.f, b3 = 0.f;
            #pragma unroll
            for (int q = 0; q < 25; ++q) {
                float4 x = hB[q];
                b0 = fmaf(x.x, w[q].x, b0); b1 = fmaf(x.y, w[q].y, b1);
                b2 = fmaf(x.z, w[q].z, b2); b3 = fmaf(x.w, w[q].w, b3);
            }
            gpart_s[1][1][j] = (b0 + b1) + (b2 + b3);
        }
        __syncthreads();

        // ---- P4: z_h/c_h/c_c/inp/loss/imp (grp 0/1, st<36) ----
        if (grp < 2 && st < Fn) {
            float a = bf_s[st];
            #pragma unroll
            for (int f = 0; f < Fn; ++f) a = fmaf(xc_s[c][f], Wf_s[st][f], a);
            float zh = a;
            float al = alpha_s[c][st], xh = xh_s[c][st];
            float ch = al * zh + (1.f - al) * xh;
            float m = inc[st], rt = inc[2 * Fn + st];
            float cc = m * rt + (1.f - m) * ch;
            inp_s[c][st] = cc;
            inp_s[c][Fn + st] = m;
            loss_acc = fmaf((fabsf(rt - xh) + fabsf(rt - zh) + fabsf(rt - ch)) * m,
                            invd_s[t], loss_acc);
            imp_b[t * Fn + st] = cc + inc[4 * Fn + st] + inc[3 * Fn + st];
        }
        __syncthreads();

        // ---- P5: gate inp+h[0:28) partial dots (grp 0/1, half 0), both chains ----
        if (grp < 2) {
            const float4* xA = (const float4*)(&inp_s[0][0]);
            const float4* hA = (const float4*)(&h_s[0][0]);
            float a0 = bias_j, a1 = 0.f, a2 = 0.f, a3 = 0.f;
            #pragma unroll
            for (int q = 0; q < 18; ++q) {
                float4 x = xA[q];
                a0 = fmaf(x.x, w[q].x, a0); a1 = fmaf(x.y, w[q].y, a1);
                a2 = fmaf(x.z, w[q].z, a2); a3 = fmaf(x.w, w[q].w, a3);
            }
            #pragma unroll
            for (int q = 0; q < 7; ++q) {
                float4 x = hA[q];
                a0 = fmaf(x.x, w[18 + q].x, a0); a1 = fmaf(x.y, w[18 + q].y, a1);
                a2 = fmaf(x.z, w[18 + q].z, a2); a3 = fmaf(x.w, w[18 + q].w, a3);
            }
            gpart_s[0][0][j] = (a0 + a1) + (a2 + a3);
            const float4* xB = (const float4*)(&inp_s[1][0]);
            const float4* hB = (const float4*)(&h_s[1][0]);
            float b0 = bias_j, b1 = 0.f, b2 = 0.f, b3 = 0.f;
            #pragma unroll
            for (int q = 0; q < 18; ++q) {
                float4 x = xB[q];
                b0 = fmaf(x.x, w[q].x, b0); b1 = fmaf(x.y, w[q].y, b1);
                b2 = fmaf(x.z, w[q].z, b2); b3 = fmaf(x.w, w[q].w, b3);
            }
            #pragma unroll
            for (int q = 0; q < 7; ++q) {
                float4 x = hB[q];
                b0 = fmaf(x.x, w[18 + q].x, b0); b1 = fmaf(x.y, w[18 + q].y, b1);
                b2 = fmaf(x.z, w[18 + q].z, b2); b3 = fmaf(x.w, w[18 + q].w, b3);
            }
            gpart_s[1][0][j] = (b0 + b1) + (b2 + b3);
        }
        __syncthreads();

        // ---- P6: LSTM (grp 0/1, st<128) ; loaders write prefetched inputs ----
        if (grp < 2) {
            if (st < Hn) {
                float ig = gpart_s[c][0][st]           + gpart_s[c][1][st];
                float fg = gpart_s[c][0][Hn + st]      + gpart_s[c][1][Hn + st];
                float gg = gpart_s[c][0][2 * Hn + st]  + gpart_s[c][1][2 * Hn + st];
                float og = gpart_s[c][0][3 * Hn + st]  + gpart_s[c][1][3 * Hn + st];
                c_reg = sigmoid_f(fg) * c_reg + sigmoid_f(ig) * tanh_f(gg);
                h_s[c][st] = sigmoid_f(og) * tanh_f(c_reg);
            }
        } else if (lddst) {
            lddst[nxt * 360] = pf;        // parity stride = 2*5*36 floats
        }
        __syncthreads();
    }

    // ---- per-chain loss partial (fixed order -> deterministic) ----
    float wkk;
    {
        float w0 = W_comb[0], w1 = W_comb[1], w2 = W_comb[2];
        float mx = fmaxf(w0, fmaxf(w1, w2));
        float e0 = expf(w0 - mx), e1 = expf(w1 - mx), e2 = expf(w2 - mx);
        wkk = ((k == 0) ? e0 : (k == 1) ? e1 : e2) / (e0 + e1 + e2);
    }
    if (grp < 2 && st < Fn) gpart_s[c][0][st] = loss_acc;
    __syncthreads();
    if (grp < 2 && st == 0) {
        float s = 0.f;
        for (int i = 0; i < Fn; ++i) s += gpart_s[c][0][i];
        ws[LOSS_OFF + myChain] = s * wkk;
    }
}

// ---------------- k-reduction of imputations ----------------
__global__ void impute_reduce(const float* __restrict__ ws,
                              const float* __restrict__ W_comb,
                              float* __restrict__ out) {
    int idx = blockIdx.x * 256 + threadIdx.x;   // < BTFn exactly
    float w0 = W_comb[0], w1 = W_comb[1], w2 = W_comb[2];
    float mx = fmaxf(w0, fmaxf(w1, w2));
    float e0 = expf(w0 - mx), e1 = expf(w1 - mx), e2 = expf(w2 - mx);
    float inv = 1.f / (e0 + e1 + e2);
    const float* imp = ws + IMP_OFF;
    out[1 + idx] = (e0 * imp[idx] + e1 * imp[BTFn + idx] + e2 * imp[2 * BTFn + idx]) * inv;
}

// ---------------- final loss ----------------
__global__ void loss_final(const float* __restrict__ ws,
                           const float* __restrict__ W_comb,
                           float* __restrict__ out) {
    int tid = threadIdx.x;
    __shared__ float red[256];
    const float* lp = ws + LOSS_OFF;
    float s = lp[tid];
    if (tid < 128) s += lp[tid + 256];
    red[tid] = s;
    __syncthreads();
    for (int off = 128; off > 0; off >>= 1) {
        if (tid < off) red[tid] += red[tid + off];
        __syncthreads();
    }
    if (tid == 0) {
        float w0 = W_comb[0], w1 = W_comb[1], w2 = W_comb[2];
        float mx = fmaxf(w0, fmaxf(w1, w2));
        float e0 = expf(w0 - mx), e1 = expf(w1 - mx), e2 = expf(w2 - mx);
        float inv = 1.f / (e0 + e1 + e2);
        float wk0 = e0 * inv, wk1 = e1 * inv, wk2 = e2 * inv;
        float reg = 0.1f * (wk0 * (1.f / 24.f) + wk1 * (1.f / 168.f) + wk2 * (1.f / 720.f));
        out[0] = red[0] + (float)Tn * reg;
    }
}

extern "C" void kernel_launch(void* const* d_in, const int* in_sizes, int n_in,
                              void* d_out, int out_size, void* d_ws, size_t ws_size,
                              hipStream_t stream) {
    const float* data   = (const float*)d_in[0];
    const float* W_dh   = (const float*)d_in[1];
    const float* b_dh   = (const float*)d_in[2];
    const float* W_dx   = (const float*)d_in[3];
    const float* b_dx   = (const float*)d_in[4];
    const float* W_hist = (const float*)d_in[5];
    const float* b_hist = (const float*)d_in[6];
    const float* W_feat = (const float*)d_in[7];
    const float* b_feat = (const float*)d_in[8];
    const float* W_wc   = (const float*)d_in[9];
    const float* b_wc   = (const float*)d_in[10];
    const float* W_ih   = (const float*)d_in[11];
    const float* W_hh   = (const float*)d_in[12];
    const float* b_ih   = (const float*)d_in[13];
    const float* b_hh   = (const float*)d_in[14];
    const float* W_comb = (const float*)d_in[15];
    float* ws = (float*)d_ws;
    float* out = (float*)d_out;

    hipLaunchKernelGGL(prep_kernel, dim3(Tn), dim3(256), 0, stream, data, ws);
    hipLaunchKernelGGL(rits_main, dim3(Bn * 3 / 2), dim3(1024), 0, stream,
                       data, W_dh, b_dh, W_dx, b_dx, W_hist, b_hist,
                       W_feat, b_feat, W_wc, b_wc, W_ih, W_hh, b_ih, b_hh, W_comb, ws);
    hipLaunchKernelGGL(impute_reduce, dim3(BTFn / 256), dim3(256), 0, stream, ws, W_comb, out);
    hipLaunchKernelGGL(loss_final, dim3(1), dim3(256), 0, stream, ws, W_comb, out);
}

// Round 6
// 1575.787 us; speedup vs baseline: 3.5932x; 1.3395x over previous
//
#include <hip/hip_runtime.h>
#include <math.h>

#define Bn 128
#define Tn 256
#define Fn 36
#define Hn 128
#define G4 512
#define BTFn (Bn*Tn*Fn)

// workspace layout (floats)
#define INVD_OFF 0
#define LOSS_OFF 102656
#define IMP_OFF  103040

// ---- LDS word offsets (all multiples of 4 for float4 access) ----
#define OFF_WHH   0          // [kk4<32][r<512][e<2] packed f16 pairs : 32768
#define OFF_WHIST 32768      // [q<64][f<36]                          : 2304
#define OFF_WF    35072      // [q<18][g<36]                          : 648
#define OFF_WWC   35720      // [q<36][g<36]                          : 1296
#define OFF_IN    37016      // f32 [c<2][w<5][f<36]                  : 360
#define OFF_DP    37376      // [par<2][c<2] stride 20                : 80
#define OFF_MP    37456      // [par<2][c<2] stride 20                : 80
#define OFF_GXP   37536      // [c<2] stride 20                       : 40
#define OFF_XCP   37576      // [c<2] stride 20                       : 40
#define OFF_CCP   37616      // [c<2] stride 20                       : 40
#define OFF_ALPHA 37656      // f32 [c<2][36]                         : 72
#define OFF_HP    37728      // [c<2][64]                             : 128
#define OFF_GF    37856      // f32 [c<2][512]                        : 1024
#define OFF_BDH   38880      // f32 [128]
#define OFF_BH    39008
#define OFF_BF    39044
#define OFF_BWC   39080
#define OFF_WDXD  39116
#define OFF_BDX   39152      // +36 -> total 39188 words
#define SMEM_WORDS 39188     // 156752 bytes < 160 KiB

typedef _Float16 h2_t __attribute__((ext_vector_type(2)));

__device__ __forceinline__ unsigned int bcu(float x) { return __builtin_bit_cast(unsigned int, x); }
__device__ __forceinline__ unsigned int pkh(float a, float b) {
    return __builtin_bit_cast(unsigned int, __builtin_amdgcn_cvt_pkrtz(a, b));
}
__device__ __forceinline__ float dot2(unsigned int a, unsigned int b, float c) {
    return __builtin_amdgcn_fdot2(__builtin_bit_cast(h2_t, a), __builtin_bit_cast(h2_t, b), c, false);
}
__device__ __forceinline__ float sigmoid_f(float x) {
    return __builtin_amdgcn_rcpf(1.f + __expf(-x));
}
__device__ __forceinline__ float tanh_f(float x) {
    return fmaf(2.f, __builtin_amdgcn_rcpf(1.f + __expf(-2.f * x)), -1.f);
}

// ---------------- prep: inv-denom per t ----------------
__global__ void prep_kernel(const float* __restrict__ data,
                            float* __restrict__ ws) {
    int t = blockIdx.x;
    int tid = threadIdx.x;
    __shared__ float red[256];
    float s = 0.f;
    for (int idx = tid; idx < Bn * Fn; idx += 256) {
        int b = idx / Fn, f = idx - b * Fn;
        s += data[((size_t)(b * 24 + 1) * Tn + t) * Fn + f];
    }
    red[tid] = s;
    __syncthreads();
    for (int off = 128; off > 0; off >>= 1) {
        if (tid < off) red[tid] += red[tid + off];
        __syncthreads();
    }
    if (tid == 0) ws[INVD_OFF + t] = 1.f / (red[0] + 1e-5f);
}

// load 18 packed words from LDS via vector reads (base must be %4==0)
#define LOAD18(dst, smem, base) do {                                      \
    float4 _a = *(const float4*)&(smem)[(base)];                          \
    float4 _b = *(const float4*)&(smem)[(base)+4];                        \
    float4 _c = *(const float4*)&(smem)[(base)+8];                        \
    float4 _d = *(const float4*)&(smem)[(base)+12];                       \
    float2 _e = *(const float2*)&(smem)[(base)+16];                       \
    dst[0]=bcu(_a.x);dst[1]=bcu(_a.y);dst[2]=bcu(_a.z);dst[3]=bcu(_a.w);  \
    dst[4]=bcu(_b.x);dst[5]=bcu(_b.y);dst[6]=bcu(_b.z);dst[7]=bcu(_b.w);  \
    dst[8]=bcu(_c.x);dst[9]=bcu(_c.y);dst[10]=bcu(_c.z);dst[11]=bcu(_c.w);\
    dst[12]=bcu(_d.x);dst[13]=bcu(_d.y);dst[14]=bcu(_d.z);dst[15]=bcu(_d.w);\
    dst[16]=bcu(_e.x);dst[17]=bcu(_e.y);                                  \
} while (0)

// ---------------- main: 512 threads, 2 chains, f16 weights (LDS + 36-reg W_ih) ----------------
__global__ __launch_bounds__(512) void rits_main(
    const float* __restrict__ data,
    const float* __restrict__ W_dh, const float* __restrict__ b_dh,
    const float* __restrict__ W_dx, const float* __restrict__ b_dx,
    const float* __restrict__ W_hist, const float* __restrict__ b_hist,
    const float* __restrict__ W_feat, const float* __restrict__ b_feat,
    const float* __restrict__ W_wc, const float* __restrict__ b_wc,
    const float* __restrict__ W_ih, const float* __restrict__ W_hh,
    const float* __restrict__ b_ih, const float* __restrict__ b_hh,
    const float* __restrict__ W_comb,
    float* __restrict__ ws) {

    extern __shared__ unsigned int smem[];
    float* smf = (float*)smem;

    const int tid = threadIdx.x;
    const int chainA = blockIdx.x * 2, chainB = chainA + 1;
    const int bA = chainA / 3, kA = chainA - 3 * bA;
    const int bB = chainB / 3, kB = chainB - 3 * bB;

    // ---- one-time staging: pack weights to f16 pairs in LDS ----
    for (int i = tid; i < 32768; i += 512) {
        int kk4 = i >> 10, rest = i & 1023, r = rest >> 1, e = rest & 1;
        int col = 4 * kk4 + 2 * e;
        smem[OFF_WHH + i] = pkh(W_hh[r * Hn + col], W_hh[r * Hn + col + 1]);
    }
    for (int i = tid; i < 64 * Fn; i += 512) {
        int q = i / Fn, f = i - q * Fn;
        smem[OFF_WHIST + i] = pkh(W_hist[f * Hn + 2 * q], W_hist[f * Hn + 2 * q + 1]);
    }
    for (int i = tid; i < 18 * Fn; i += 512) {
        int q = i / Fn, g = i - q * Fn;
        float w0 = (2 * q     == g) ? 0.f : W_feat[g * Fn + 2 * q];
        float w1 = (2 * q + 1 == g) ? 0.f : W_feat[g * Fn + 2 * q + 1];
        smem[OFF_WF + i] = pkh(w0, w1);
    }
    for (int i = tid; i < 36 * Fn; i += 512) {
        int q = i / Fn, g = i - q * Fn;
        int col = (q < 18) ? 2 * q : Fn + 2 * (q - 18);
        smem[OFF_WWC + i] = pkh(W_wc[g * 2 * Fn + col], W_wc[g * 2 * Fn + col + 1]);
    }
    if (tid < Hn) smf[OFF_BDH + tid] = b_dh[tid];
    if (tid < Fn) {
        smf[OFF_BH + tid] = b_hist[tid]; smf[OFF_BF + tid] = b_feat[tid];
        smf[OFF_BWC + tid] = b_wc[tid];  smf[OFF_WDXD + tid] = W_dx[tid * Fn + tid];
        smf[OFF_BDX + tid] = b_dx[tid];
    }

    // ---- W_ih row j -> 36 packed regs; W_dh row (tid&127) -> 18 packed regs ----
    unsigned int wih[36];
    #pragma unroll
    for (int q = 0; q < 36; ++q)
        wih[q] = pkh(W_ih[tid * 2 * Fn + 2 * q], W_ih[tid * 2 * Fn + 2 * q + 1]);
    const float bias_j = b_ih[tid] + b_hh[tid];
    unsigned int wdh[18];
    {
        int hidx = tid & 127;
        #pragma unroll
        for (int q = 0; q < 18; ++q)
            wdh[q] = pkh(W_dh[hidx * Fn + 2 * q], W_dh[hidx * Fn + 2 * q + 1]);
    }

    // ---- loader roles (tid>=256): slot1 e=idx, slot2 e=idx+256 (<360) ----
    const float* ldsrc1 = nullptr; int lddst1 = 0, c1 = 0, f1 = 0; bool isd1 = false, ism1 = false;
    const float* ldsrc2 = nullptr; int lddst2 = -1;
    if (tid >= 256) {
        int idx = tid - 256;
        {
            int e = idx; int c = (e >= 180); int r = e - c * 180;
            int w = r / Fn, f = r - w * Fn;
            int bb = c ? bB : bA, kk = c ? kB : kA;
            int row = (w == 0) ? 1 : (w == 1) ? 2 : (3 + 3 * kk + (w - 2));
            ldsrc1 = data + (size_t)(bb * 24 + row) * Tn * Fn + f;
            lddst1 = OFF_IN + (c * 5 + w) * Fn + f;
            isd1 = (w == 1); ism1 = (w == 0); c1 = c; f1 = f;
        }
        if (idx < 104) {
            int e = idx + 256; int r = e - 180;           // always chain 1
            int w = r / Fn, f = r - w * Fn;
            int row = 3 + 3 * kB + (w - 2);
            ldsrc2 = data + (size_t)(bB * 24 + row) * Tn * Fn + f;
            lddst2 = OFF_IN + (5 + w) * Fn + f;
        }
        // prologue t=0 -> in_s + d/m packs (parity 0)
        float v1 = ldsrc1[0];
        smf[lddst1] = v1;
        float v1n = __shfl_xor(v1, 1);
        if (isd1 && !(f1 & 1)) smem[OFF_DP + c1 * 20 + (f1 >> 1)] = pkh(v1, v1n);
        if (ism1 && !(f1 & 1)) smem[OFF_MP + c1 * 20 + (f1 >> 1)] = pkh(v1, v1n);
        if (ldsrc2) smf[lddst2] = ldsrc2[0];
    }

    const float* invd_g = ws + INVD_OFF;
    float* impA = ws + IMP_OFF + (size_t)(kA * Bn + bA) * Tn * Fn;
    float* impB = ws + IMP_OFF + (size_t)(kB * Bn + bB) * Tn * Fn;

    float h_reg = 0.f, c_reg = 0.f, loss_acc = 0.f;
    __syncthreads();

    for (int t = 0; t < Tn; ++t) {
        const int cur = t & 1, nxt = cur ^ 1;

        // ---- P2: decay h + pack hp (tid<256); gamma_x + pack (256..383) ----
        if (tid < 256) {
            const int c = tid >> 7, hidx = tid & 127;
            float g = smf[OFF_BDH + hidx];
            const int db = OFF_DP + (cur * 2 + c) * 20;
            #pragma unroll
            for (int q = 0; q < 18; ++q) g = dot2(smem[db + q], wdh[q], g);
            h_reg *= __expf(-fmaxf(g, 0.f));
            float hn = __shfl_xor(h_reg, 1);
            if (!(hidx & 1)) smem[OFF_HP + c * 64 + (hidx >> 1)] = pkh(h_reg, hn);
        } else if (tid < 384) {
            int u = tid - 256, c = u >> 6, f = u & 63;
            if (f < Fn) {
                float d = smf[OFF_IN + (c * 5 + 1) * Fn + f];
                float gx = __expf(-fmaxf(fmaf(d, smf[OFF_WDXD + f], smf[OFF_BDX + f]), 0.f));
                float gxn = __shfl_xor(gx, 1);
                if (!(f & 1)) smem[OFF_GXP + c * 20 + (f >> 1)] = pkh(gx, gxn);
            }
        }
        __syncthreads();   // B1

        // ---- P3: feature pipeline (waves 0-1) | alpha (waves 2-3) | gates-hh (waves 4-7) ----
        float xh = 0.f, zh = 0.f, pf1v = 0.f, pf2v = 0.f;
        if (tid < 128) {
            const int c = tid >> 6, f = tid & 63;
            if (f < Fn) {
                float a = smf[OFF_BH + f];
                #pragma unroll
                for (int ch = 0; ch < 8; ++ch) {
                    float4 hL = *(const float4*)&smem[OFF_HP + c * 64 + ch * 8];
                    float4 hH = *(const float4*)&smem[OFF_HP + c * 64 + ch * 8 + 4];
                    a = dot2(bcu(hL.x), smem[OFF_WHIST + (ch * 8 + 0) * Fn + f], a);
                    a = dot2(bcu(hL.y), smem[OFF_WHIST + (ch * 8 + 1) * Fn + f], a);
                    a = dot2(bcu(hL.z), smem[OFF_WHIST + (ch * 8 + 2) * Fn + f], a);
                    a = dot2(bcu(hL.w), smem[OFF_WHIST + (ch * 8 + 3) * Fn + f], a);
                    a = dot2(bcu(hH.x), smem[OFF_WHIST + (ch * 8 + 4) * Fn + f], a);
                    a = dot2(bcu(hH.y), smem[OFF_WHIST + (ch * 8 + 5) * Fn + f], a);
                    a = dot2(bcu(hH.z), smem[OFF_WHIST + (ch * 8 + 6) * Fn + f], a);
                    a = dot2(bcu(hH.w), smem[OFF_WHIST + (ch * 8 + 7) * Fn + f], a);
                }
                xh = a;
                float m = smf[OFF_IN + (c * 5 + 0) * Fn + f];
                float rt = smf[OFF_IN + (c * 5 + 2) * Fn + f];
                float xc = m * rt + (1.f - m) * xh;
                float xcn = __shfl_xor(xc, 1);
                if (!(f & 1)) smem[OFF_XCP + c * 20 + (f >> 1)] = pkh(xc, xcn);
                float z = smf[OFF_BF + f];
                #pragma unroll
                for (int q = 0; q < 18; ++q)
                    z = dot2(smem[OFF_XCP + c * 20 + q], smem[OFF_WF + q * Fn + f], z);
                zh = z;
            }
        } else if (tid < 256) {
            const int c = (tid - 128) >> 6, g = (tid - 128) & 63;
            if (g < Fn) {
                float a = smf[OFF_BWC + g];
                #pragma unroll
                for (int q = 0; q < 18; ++q)
                    a = dot2(smem[OFF_GXP + c * 20 + q], smem[OFF_WWC + q * Fn + g], a);
                #pragma unroll
                for (int q = 0; q < 18; ++q)
                    a = dot2(smem[OFF_MP + (cur * 2 + c) * 20 + q], smem[OFF_WWC + (18 + q) * Fn + g], a);
                smf[OFF_ALPHA + c * Fn + g] = a;
            }
        } else {
            // issue t+1 loads early (latency hides under the dots below)
            pf1v = ldsrc1[(size_t)(t + 1) * Fn];
            if (ldsrc2) pf2v = ldsrc2[(size_t)(t + 1) * Fn];
            // gates-hh for rows r0=tid-256, r1=tid, both chains
            const int r0 = tid - 256, r1 = tid;
            float A0 = 0.f, B0 = 0.f, A1 = 0.f, B1v = 0.f;
            #pragma unroll
            for (int ch = 0; ch < 8; ++ch) {
                float4 aL = *(const float4*)&smem[OFF_HP + ch * 8];
                float4 aH = *(const float4*)&smem[OFF_HP + ch * 8 + 4];
                float4 bL = *(const float4*)&smem[OFF_HP + 64 + ch * 8];
                float4 bH = *(const float4*)&smem[OFF_HP + 64 + ch * 8 + 4];
                unsigned int ua0=bcu(aL.x),ua1=bcu(aL.y),ua2=bcu(aL.z),ua3=bcu(aL.w);
                unsigned int ua4=bcu(aH.x),ua5=bcu(aH.y),ua6=bcu(aH.z),ua7=bcu(aH.w);
                unsigned int ub0=bcu(bL.x),ub1=bcu(bL.y),ub2=bcu(bL.z),ub3=bcu(bL.w);
                unsigned int ub4=bcu(bH.x),ub5=bcu(bH.y),ub6=bcu(bH.z),ub7=bcu(bH.w);
                #define HH_STEP(s, uaE, uaO, ubE, ubO)                                  \
                {   const int kk4 = ch * 4 + (s);                                       \
                    float2 w0 = *(const float2*)&smem[OFF_WHH + (kk4 * G4 + r0) * 2];   \
                    float2 w1 = *(const float2*)&smem[OFF_WHH + (kk4 * G4 + r1) * 2];   \
                    unsigned int w00=bcu(w0.x), w01=bcu(w0.y);                          \
                    unsigned int w10=bcu(w1.x), w11=bcu(w1.y);                          \
                    A0 = dot2(uaE, w00, A0); A0 = dot2(uaO, w01, A0);                   \
                    B0 = dot2(ubE, w00, B0); B0 = dot2(ubO, w01, B0);                   \
                    A1 = dot2(uaE, w10, A1); A1 = dot2(uaO, w11, A1);                   \
                    B1v = dot2(ubE, w10, B1v); B1v = dot2(ubO, w11, B1v);               \
                }
                HH_STEP(0, ua0, ua1, ub0, ub1)
                HH_STEP(1, ua2, ua3, ub2, ub3)
                HH_STEP(2, ua4, ua5, ub4, ub5)
                HH_STEP(3, ua6, ua7, ub6, ub7)
                #undef HH_STEP
            }
            smf[OFF_GF + r0] = A0;  smf[OFF_GF + G4 + r0] = B0;
            smf[OFF_GF + r1] = A1;  smf[OFF_GF + G4 + r1] = B1v;
        }
        __syncthreads();   // B2

        // ---- P4: c_h / cc / loss / imp / ccp pack (waves 0-1) ----
        if (tid < 128) {
            const int c = tid >> 6, f = tid & 63;
            if (f < Fn) {
                float al = smf[OFF_ALPHA + c * Fn + f];
                float chv = al * zh + (1.f - al) * xh;
                float m = smf[OFF_IN + (c * 5 + 0) * Fn + f];
                float rt = smf[OFF_IN + (c * 5 + 2) * Fn + f];
                float cc = m * rt + (1.f - m) * chv;
                loss_acc = fmaf((fabsf(rt - xh) + fabsf(rt - zh) + fabsf(rt - chv)) * m,
                                invd_g[t], loss_acc);
                float tr = smf[OFF_IN + (c * 5 + 3) * Fn + f];
                float se = smf[OFF_IN + (c * 5 + 4) * Fn + f];
                ((c == 0) ? impA : impB)[t * Fn + f] = cc + se + tr;
                float ccn = __shfl_xor(cc, 1);
                if (!(f & 1)) smem[OFF_CCP + c * 20 + (f >> 1)] = pkh(cc, ccn);
            }
        }
        __syncthreads();   // B3

        // ---- P5: gates-ih (all threads, row j=tid); loaders write t+1 inputs ----
        {
            const int j = tid;
            float gA = smf[OFF_GF + j] + bias_j;
            float gB = smf[OFF_GF + G4 + j] + bias_j;
            unsigned int buf[18];
            LOAD18(buf, smem, OFF_CCP + 0 * 20);
            #pragma unroll
            for (int q = 0; q < 18; ++q) gA = dot2(buf[q], wih[q], gA);
            LOAD18(buf, smem, OFF_CCP + 1 * 20);
            #pragma unroll
            for (int q = 0; q < 18; ++q) gB = dot2(buf[q], wih[q], gB);
            LOAD18(buf, smem, OFF_MP + (cur * 2 + 0) * 20);
            #pragma unroll
            for (int q = 0; q < 18; ++q) gA = dot2(buf[q], wih[18 + q], gA);
            LOAD18(buf, smem, OFF_MP + (cur * 2 + 1) * 20);
            #pragma unroll
            for (int q = 0; q < 18; ++q) gB = dot2(buf[q], wih[18 + q], gB);
            smf[OFF_GF + j] = gA;
            smf[OFF_GF + G4 + j] = gB;
        }
        if (tid >= 256) {
            smf[lddst1] = pf1v;
            float vn = __shfl_xor(pf1v, 1);
            if (isd1 && !(f1 & 1)) smem[OFF_DP + (nxt * 2 + c1) * 20 + (f1 >> 1)] = pkh(pf1v, vn);
            if (ism1 && !(f1 & 1)) smem[OFF_MP + (nxt * 2 + c1) * 20 + (f1 >> 1)] = pkh(pf1v, vn);
            if (ldsrc2) smf[lddst2] = pf2v;
        }
        __syncthreads();   // B4

        // ---- P6: LSTM (tid<256) ----
        if (tid < 256) {
            const int c = tid >> 7, hidx = tid & 127;
            float ig = smf[OFF_GF + c * G4 + hidx];
            float fg = smf[OFF_GF + c * G4 + 128 + hidx];
            float gg = smf[OFF_GF + c * G4 + 256 + hidx];
            float og = smf[OFF_GF + c * G4 + 384 + hidx];
            c_reg = sigmoid_f(fg) * c_reg + sigmoid_f(ig) * tanh_f(gg);
            h_reg = sigmoid_f(og) * tanh_f(c_reg);
        }
        // no barrier needed: next P2 writes hp (last read before B2), next P3 writes GF (after B1)
    }

    // ---- per-block loss partial (fixed order -> deterministic) ----
    if (tid < 128) {
        const int c = tid >> 6, f = tid & 63;
        if (f < Fn) smf[OFF_GF + c * Fn + f] = loss_acc;
    }
    __syncthreads();
    if (tid == 0) {
        float sA = 0.f, sB = 0.f;
        for (int i = 0; i < Fn; ++i) { sA += smf[OFF_GF + i]; sB += smf[OFF_GF + Fn + i]; }
        float w0 = W_comb[0], w1 = W_comb[1], w2 = W_comb[2];
        float mx = fmaxf(w0, fmaxf(w1, w2));
        float e0 = expf(w0 - mx), e1 = expf(w1 - mx), e2 = expf(w2 - mx);
        float inv = 1.f / (e0 + e1 + e2);
        float wkA = ((kA == 0) ? e0 : (kA == 1) ? e1 : e2) * inv;
        float wkB = ((kB == 0) ? e0 : (kB == 1) ? e1 : e2) * inv;
        ws[LOSS_OFF + blockIdx.x] = sA * wkA + sB * wkB;
    }
}

// ---------------- k-reduction of imputations ----------------
__global__ void impute_reduce(const float* __restrict__ ws,
                              const float* __restrict__ W_comb,
                              float* __restrict__ out) {
    int idx = blockIdx.x * 256 + threadIdx.x;
    float w0 = W_comb[0], w1 = W_comb[1], w2 = W_comb[2];
    float mx = fmaxf(w0, fmaxf(w1, w2));
    float e0 = expf(w0 - mx), e1 = expf(w1 - mx), e2 = expf(w2 - mx);
    float inv = 1.f / (e0 + e1 + e2);
    const float* imp = ws + IMP_OFF;
    out[1 + idx] = (e0 * imp[idx] + e1 * imp[BTFn + idx] + e2 * imp[2 * BTFn + idx]) * inv;
}

// ---------------- final loss (192 per-block partials) ----------------
__global__ void loss_final(const float* __restrict__ ws,
                           const float* __restrict__ W_comb,
                           float* __restrict__ out) {
    int tid = threadIdx.x;
    __shared__ float red[256];
    const float* lp = ws + LOSS_OFF;
    red[tid] = (tid < 192) ? lp[tid] : 0.f;
    __syncthreads();
    for (int off = 128; off > 0; off >>= 1) {
        if (tid < off) red[tid] += red[tid + off];
        __syncthreads();
    }
    if (tid == 0) {
        float w0 = W_comb[0], w1 = W_comb[1], w2 = W_comb[2];
        float mx = fmaxf(w0, fmaxf(w1, w2));
        float e0 = expf(w0 - mx), e1 = expf(w1 - mx), e2 = expf(w2 - mx);
        float inv = 1.f / (e0 + e1 + e2);
        float wk0 = e0 * inv, wk1 = e1 * inv, wk2 = e2 * inv;
        float reg = 0.1f * (wk0 * (1.f / 24.f) + wk1 * (1.f / 168.f) + wk2 * (1.f / 720.f));
        out[0] = red[0] + (float)Tn * reg;
    }
}

extern "C" void kernel_launch(void* const* d_in, const int* in_sizes, int n_in,
                              void* d_out, int out_size, void* d_ws, size_t ws_size,
                              hipStream_t stream) {
    const float* data   = (const float*)d_in[0];
    const float* W_dh   = (const float*)d_in[1];
    const float* b_dh   = (const float*)d_in[2];
    const float* W_dx   = (const float*)d_in[3];
    const float* b_dx   = (const float*)d_in[4];
    const float* W_hist = (const float*)d_in[5];
    const float* b_hist = (const float*)d_in[6];
    const float* W_feat = (const float*)d_in[7];
    const float* b_feat = (const float*)d_in[8];
    const float* W_wc   = (const float*)d_in[9];
    const float* b_wc   = (const float*)d_in[10];
    const float* W_ih   = (const float*)d_in[11];
    const float* W_hh   = (const float*)d_in[12];
    const float* b_ih   = (const float*)d_in[13];
    const float* b_hh   = (const float*)d_in[14];
    const float* W_comb = (const float*)d_in[15];
    float* ws = (float*)d_ws;
    float* out = (float*)d_out;

    hipLaunchKernelGGL(prep_kernel, dim3(Tn), dim3(256), 0, stream, data, ws);
    hipLaunchKernelGGL(rits_main, dim3(Bn * 3 / 2), dim3(512), SMEM_WORDS * 4, stream,
                       data, W_dh, b_dh, W_dx, b_dx, W_hist, b_hist,
                       W_feat, b_feat, W_wc, b_wc, W_ih, W_hh, b_ih, b_hh, W_comb, ws);
    hipLaunchKernelGGL(impute_reduce, dim3(BTFn / 256), dim3(256), 0, stream, ws, W_comb, out);
    hipLaunchKernelGGL(loss_final, dim3(1), dim3(256), 0, stream, ws, W_comb, out);
}